// Round 1
// baseline (531.919 us; speedup 1.0000x reference)
//
#include <hip/hip_runtime.h>

#define NB 8
#define NPTS 4096
// scale: sum of all 2*8*4096 mins / (4096*8)
#define OUT_SCALE (1.0f / (float)(NPTS * NB))

// Prep: for each set (x,y), batch, point: write float4 {-2px, -2py, -2pz, ||p||^2}.
// Also zeroes the output accumulator (d_out is poisoned before every timed call).
__global__ void prep_kernel(const float* __restrict__ x, const float* __restrict__ y,
                            float4* __restrict__ wx, float4* __restrict__ wy,
                            float* __restrict__ out) {
    int idx = blockIdx.x * blockDim.x + threadIdx.x;   // 0 .. 2*8*4096-1
    if (idx == 0) out[0] = 0.0f;
    int set = idx >> 15;           // 0: x, 1: y
    int r   = idx & 32767;
    int b   = r >> 12;             // batch
    int m   = r & 4095;            // point
    const float* src = (set == 0) ? x : y;
    float4* dst      = (set == 0) ? wx : wy;
    const float* base = src + (size_t)b * 3 * NPTS + m;
    float px = base[0];
    float py = base[NPTS];
    float pz = base[2 * NPTS];
    float4 v;
    v.x = -2.0f * px;
    v.y = -2.0f * py;
    v.z = -2.0f * pz;
    v.w = px * px + py * py + pz * pz;
    dst[(size_t)b * NPTS + m] = v;
}

// Main: one thread per a-point. dir 0: A=x vs prep(y); dir 1: A=y vs prep(x).
// d(a, q) = ||a||^2 + q.w + a.x*q.x + a.y*q.y + a.z*q.z   (q holds -2b and ||b||^2)
__global__ __launch_bounds__(256) void chamfer_main(
    const float* __restrict__ x, const float* __restrict__ y,
    const float4* __restrict__ wx, const float4* __restrict__ wy,
    float* __restrict__ out) {
    const int b   = blockIdx.y;
    const int dir = blockIdx.z;
    const float*  A  = (dir == 0) ? x : y;
    const float4* Bp = (dir == 0) ? wy : wx;

    const int i = blockIdx.x * blockDim.x + threadIdx.x;   // a-point index 0..4095
    const float* abase = A + (size_t)b * 3 * NPTS + i;
    const float ax = abase[0];
    const float ay = abase[NPTS];
    const float az = abase[2 * NPTS];
    const float xx = ax * ax + ay * ay + az * az;

    const float4* __restrict__ q = Bp + (size_t)b * NPTS;

    float vmin = 3.4e38f;
#pragma unroll 8
    for (int m = 0; m < NPTS; ++m) {
        float4 c = q[m];                 // wave-uniform -> scalar load expected
        float t = fmaf(ax, c.x, xx);
        t = fmaf(ay, c.y, t);
        t = fmaf(az, c.z, t);
        t = t + c.w;
        vmin = fminf(vmin, t);
    }

    // per-wave reduction of mins (sum), then one atomic per wave
    float s = vmin;
#pragma unroll
    for (int off = 32; off > 0; off >>= 1) s += __shfl_down(s, off, 64);
    if ((threadIdx.x & 63) == 0) atomicAdd(out, s * OUT_SCALE);
}

// Fallback if workspace is too small: read raw B coords (7 VALU ops/pair).
__global__ void zero_out(float* out) { out[0] = 0.0f; }

__global__ __launch_bounds__(256) void chamfer_direct(
    const float* __restrict__ x, const float* __restrict__ y,
    float* __restrict__ out) {
    const int b   = blockIdx.y;
    const int dir = blockIdx.z;
    const float* A  = (dir == 0) ? x : y;
    const float* Bm = (dir == 0) ? y : x;

    const int i = blockIdx.x * blockDim.x + threadIdx.x;
    const float* abase = A + (size_t)b * 3 * NPTS + i;
    const float ax = abase[0];
    const float ay = abase[NPTS];
    const float az = abase[2 * NPTS];

    const float* bbase = Bm + (size_t)b * 3 * NPTS;

    float vmin = 3.4e38f;
#pragma unroll 8
    for (int m = 0; m < NPTS; ++m) {
        float dx = ax - bbase[m];
        float dy = ay - bbase[NPTS + m];
        float dz = az - bbase[2 * NPTS + m];
        float t = dx * dx;
        t = fmaf(dy, dy, t);
        t = fmaf(dz, dz, t);
        vmin = fminf(vmin, t);
    }

    float s = vmin;
#pragma unroll
    for (int off = 32; off > 0; off >>= 1) s += __shfl_down(s, off, 64);
    if ((threadIdx.x & 63) == 0) atomicAdd(out, s * OUT_SCALE);
}

extern "C" void kernel_launch(void* const* d_in, const int* in_sizes, int n_in,
                              void* d_out, int out_size, void* d_ws, size_t ws_size,
                              hipStream_t stream) {
    const float* x = (const float*)d_in[0];
    const float* y = (const float*)d_in[1];
    float* out = (float*)d_out;

    const size_t need = 2ull * NB * NPTS * sizeof(float4);   // 1 MiB
    if (ws_size >= need) {
        float4* wx = (float4*)d_ws;
        float4* wy = wx + (size_t)NB * NPTS;
        prep_kernel<<<dim3((2 * NB * NPTS) / 256), dim3(256), 0, stream>>>(x, y, wx, wy, out);
        chamfer_main<<<dim3(NPTS / 256, NB, 2), dim3(256), 0, stream>>>(x, y, wx, wy, out);
    } else {
        zero_out<<<dim3(1), dim3(1), 0, stream>>>(out);
        chamfer_direct<<<dim3(NPTS / 256, NB, 2), dim3(256), 0, stream>>>(x, y, out);
    }
}

// Round 2
// 117.353 us; speedup vs baseline: 4.5326x; 4.5326x over previous
//
#include <hip/hip_runtime.h>

#define NB 8
#define NPTS 4096
#define CH 8                        // m-chunks per (dir,b) -> occupancy
#define MCHUNK (NPTS / CH)          // 512 m per thread
#define OUT_SCALE (1.0f / (float)(NPTS * NB))

// ws layout: [wx: NB*NPTS float4][wy: NB*NPTS float4][pmin: 2*NB*CH*NPTS float]
#define WS_TABLES (2ull * NB * NPTS * sizeof(float4))
#define WS_PMIN   (2ull * NB * CH * NPTS * sizeof(float))

// Prep: per set/batch/point write float4 {-2px, -2py, -2pz, ||p||^2}; zero out[0].
__global__ void prep_kernel(const float* __restrict__ x, const float* __restrict__ y,
                            float4* __restrict__ wx, float4* __restrict__ wy,
                            float* __restrict__ out) {
    int idx = blockIdx.x * blockDim.x + threadIdx.x;   // 0 .. 2*8*4096-1
    if (idx == 0) out[0] = 0.0f;
    int set = idx >> 15;
    int r   = idx & 32767;
    int b   = r >> 12;
    int m   = r & 4095;
    const float* src = (set == 0) ? x : y;
    float4* dst      = (set == 0) ? wx : wy;
    const float* base = src + (size_t)b * 3 * NPTS + m;
    float px = base[0];
    float py = base[NPTS];
    float pz = base[2 * NPTS];
    float4 v;
    v.x = -2.0f * px;
    v.y = -2.0f * py;
    v.z = -2.0f * pz;
    v.w = px * px + py * py + pz * pz;
    dst[(size_t)b * NPTS + m] = v;
}

// Main: one thread per a-point i, over ONE m-chunk of 512. grid (16, NB, 2*CH).
// d(a, q) = ||a||^2 + q.w + a.x*q.x + a.y*q.y + a.z*q.z   (q = {-2b, ||b||^2})
__global__ __launch_bounds__(256) void chamfer_main(
    const float* __restrict__ x, const float* __restrict__ y,
    const float4* __restrict__ wx, const float4* __restrict__ wy,
    float* __restrict__ pmin) {
    const int b    = blockIdx.y;
    const int dch  = blockIdx.z;        // 0 .. 2*CH-1
    const int dir  = dch >> 3;          // CH == 8
    const int ch   = dch & (CH - 1);

    const float*  A  = (dir == 0) ? x : y;
    const float4* Bp = (dir == 0) ? wy : wx;

    const int i = blockIdx.x * blockDim.x + threadIdx.x;   // 0..4095
    const float* abase = A + (size_t)b * 3 * NPTS + i;
    const float ax = abase[0];
    const float ay = abase[NPTS];
    const float az = abase[2 * NPTS];
    const float xx = ax * ax + ay * ay + az * az;

    const float4* __restrict__ q = Bp + (size_t)b * NPTS + (size_t)ch * MCHUNK;

    float vmin = 3.4e38f;
    for (int m = 0; m < MCHUNK; m += 8) {
        float t[8];
#pragma unroll
        for (int u = 0; u < 8; ++u) {
            float4 c = q[m + u];             // wave-uniform -> scalar loads
            float tt = fmaf(ax, c.x, xx);
            tt = fmaf(ay, c.y, tt);
            tt = fmaf(az, c.z, tt);
            t[u] = tt + c.w;
        }
        // min tree (depth 3), single carried min per 8 m
        float m01 = fminf(t[0], t[1]);
        float m23 = fminf(t[2], t[3]);
        float m45 = fminf(t[4], t[5]);
        float m67 = fminf(t[6], t[7]);
        float ma = fminf(m01, m23);
        float mb = fminf(m45, m67);
        vmin = fminf(vmin, fminf(ma, mb));
    }

    // pmin index: ((dir*NB + b)*CH + ch)*NPTS + i   -- coalesced in i
    pmin[((size_t)(dir * NB + b) * CH + ch) * NPTS + i] = vmin;
}

// Reduce: 65536 threads; each mins its CH partials, block-reduces sum, 1 atomic/block.
__global__ __launch_bounds__(256) void chamfer_reduce(
    const float* __restrict__ pmin, float* __restrict__ out) {
    __shared__ float sred[4];
    const int u  = blockIdx.x * blockDim.x + threadIdx.x;  // 0 .. 2*NB*NPTS-1
    const int i  = u & (NPTS - 1);
    const int db = u >> 12;                                // dir*NB + b, 0..15
    const float* base = pmin + (size_t)db * CH * NPTS + i;
    float vm = base[0];
#pragma unroll
    for (int c = 1; c < CH; ++c) vm = fminf(vm, base[(size_t)c * NPTS]);

    float s = vm;
#pragma unroll
    for (int off = 32; off > 0; off >>= 1) s += __shfl_down(s, off, 64);
    const int lane = threadIdx.x & 63;
    const int wid  = threadIdx.x >> 6;
    if (lane == 0) sred[wid] = s;
    __syncthreads();
    if (threadIdx.x == 0) {
        float tot = sred[0] + sred[1] + sred[2] + sred[3];
        atomicAdd(out, tot * OUT_SCALE);
    }
}

// Fallback (ws too small): direct, low-occupancy version. Correctness only.
__global__ void zero_out(float* out) { out[0] = 0.0f; }

__global__ __launch_bounds__(256) void chamfer_direct(
    const float* __restrict__ x, const float* __restrict__ y,
    float* __restrict__ out) {
    const int b   = blockIdx.y;
    const int dir = blockIdx.z;
    const float* A  = (dir == 0) ? x : y;
    const float* Bm = (dir == 0) ? y : x;

    const int i = blockIdx.x * blockDim.x + threadIdx.x;
    const float* abase = A + (size_t)b * 3 * NPTS + i;
    const float ax = abase[0];
    const float ay = abase[NPTS];
    const float az = abase[2 * NPTS];

    const float* bbase = Bm + (size_t)b * 3 * NPTS;

    float vmin = 3.4e38f;
#pragma unroll 8
    for (int m = 0; m < NPTS; ++m) {
        float dx = ax - bbase[m];
        float dy = ay - bbase[NPTS + m];
        float dz = az - bbase[2 * NPTS + m];
        float t = dx * dx;
        t = fmaf(dy, dy, t);
        t = fmaf(dz, dz, t);
        vmin = fminf(vmin, t);
    }
    float s = vmin;
#pragma unroll
    for (int off = 32; off > 0; off >>= 1) s += __shfl_down(s, off, 64);
    if ((threadIdx.x & 63) == 0) atomicAdd(out, s * OUT_SCALE);
}

extern "C" void kernel_launch(void* const* d_in, const int* in_sizes, int n_in,
                              void* d_out, int out_size, void* d_ws, size_t ws_size,
                              hipStream_t stream) {
    const float* x = (const float*)d_in[0];
    const float* y = (const float*)d_in[1];
    float* out = (float*)d_out;

    if (ws_size >= WS_TABLES + WS_PMIN) {
        float4* wx  = (float4*)d_ws;
        float4* wy  = wx + (size_t)NB * NPTS;
        float*  pmin = (float*)((char*)d_ws + WS_TABLES);
        prep_kernel<<<dim3((2 * NB * NPTS) / 256), dim3(256), 0, stream>>>(x, y, wx, wy, out);
        chamfer_main<<<dim3(NPTS / 256, NB, 2 * CH), dim3(256), 0, stream>>>(x, y, wx, wy, pmin);
        chamfer_reduce<<<dim3((2 * NB * NPTS) / 256), dim3(256), 0, stream>>>(pmin, out);
    } else {
        zero_out<<<dim3(1), dim3(1), 0, stream>>>(out);
        chamfer_direct<<<dim3(NPTS / 256, NB, 2), dim3(256), 0, stream>>>(x, y, out);
    }
}

// Round 3
// 87.694 us; speedup vs baseline: 6.0656x; 1.3382x over previous
//
#include <hip/hip_runtime.h>

#define NB 8
#define NPTS 4096
#define IPT 4                      // a-points per thread
#define OUT_SCALE (1.0f / (float)(NPTS * NB))

// ---------------- main kernel: templated on CH (m-chunks per (dir,b)) ----------------
// grid: (NPTS/(256*IPT), NB, 2*CH), block 256.
// Each block: stages its MCHUNK=NPTS/CH b-points into LDS as {-2bx,-2by,-2bz,||b||^2},
// then each thread scans the chunk for IPT a-points, writes partial mins to pmin.
template <int CH_>
__global__ __launch_bounds__(256) void chamfer_main(
    const float* __restrict__ x, const float* __restrict__ y,
    float* __restrict__ pmin, float* __restrict__ out) {
    constexpr int MCHUNK = NPTS / CH_;
    __shared__ float4 qs[MCHUNK];

    const int b   = blockIdx.y;
    const int z   = blockIdx.z;          // 0 .. 2*CH-1
    const int dir = z / CH_;
    const int ch  = z % CH_;
    const int tid = threadIdx.x;

    const float* A = (dir == 0) ? x : y;
    const float* B = (dir == 0) ? y : x;

    // d_out is re-poisoned before every call; zero it here (reduce runs after all main blocks).
    if (blockIdx.x == 0 && b == 0 && z == 0 && tid == 0) out[0] = 0.0f;

    // Stage chunk into LDS with coalesced vector loads + inline prep.
    const float* bb = B + (size_t)b * 3 * NPTS + (size_t)ch * MCHUNK;
    for (int t = tid; t < MCHUNK; t += 256) {
        float bxv = bb[t];
        float byv = bb[NPTS + t];
        float bzv = bb[2 * NPTS + t];
        qs[t] = make_float4(-2.0f * bxv, -2.0f * byv, -2.0f * bzv,
                            bxv * bxv + byv * byv + bzv * bzv);
    }

    // Load IPT a-points (coalesced).
    const int i0 = blockIdx.x * (256 * IPT) + tid;
    const float* ab = A + (size_t)b * 3 * NPTS;
    float ax[IPT], ay[IPT], az[IPT], xx[IPT], vmin[IPT];
#pragma unroll
    for (int k = 0; k < IPT; ++k) {
        int i = i0 + k * 256;
        ax[k] = ab[i];
        ay[k] = ab[NPTS + i];
        az[k] = ab[2 * NPTS + i];
        xx[k] = ax[k] * ax[k] + ay[k] * ay[k] + az[k] * az[k];
        vmin[k] = 3.4e38f;
    }
    __syncthreads();

    // Inner scan: per 4 m, per a-point: 4 lds broadcasts + (4*(1 add+3 fma) + min tree).
    for (int m = 0; m < MCHUNK; m += 4) {
        float t[4][IPT];
#pragma unroll
        for (int u = 0; u < 4; ++u) {
            float4 c = qs[m + u];            // uniform addr -> ds_read_b128 broadcast
#pragma unroll
            for (int k = 0; k < IPT; ++k) {
                float s = xx[k] + c.w;
                s = fmaf(ax[k], c.x, s);
                s = fmaf(ay[k], c.y, s);
                t[u][k] = fmaf(az[k], c.z, s);
            }
        }
#pragma unroll
        for (int k = 0; k < IPT; ++k) {
            float m01 = fminf(t[0][k], t[1][k]);
            float m23 = fminf(t[2][k], t[3][k]);
            vmin[k] = fminf(vmin[k], fminf(m01, m23));   // v_min3 expected
        }
    }

    // pmin[((dir*NB+b)*CH + ch)*NPTS + i], coalesced in i.
    float* pout = pmin + ((size_t)(dir * NB + b) * CH_ + ch) * NPTS;
#pragma unroll
    for (int k = 0; k < IPT; ++k) pout[i0 + k * 256] = vmin[k];
}

// ---------------- reduce: min over CH chunks, sum everything, one atomic/block ----------------
template <int CH_>
__global__ __launch_bounds__(256) void chamfer_reduce(
    const float* __restrict__ pmin, float* __restrict__ out) {
    __shared__ float sred[4];
    const int u  = blockIdx.x * 256 + threadIdx.x;     // 0 .. 2*NB*NPTS-1
    const int i  = u & (NPTS - 1);
    const int db = u >> 12;                            // dir*NB+b
    const float* base = pmin + (size_t)db * CH_ * NPTS + i;
    float vm = base[0];
#pragma unroll
    for (int c = 1; c < CH_; ++c) vm = fminf(vm, base[(size_t)c * NPTS]);

    float s = vm;
#pragma unroll
    for (int off = 32; off > 0; off >>= 1) s += __shfl_down(s, off, 64);
    const int lane = threadIdx.x & 63;
    const int wid  = threadIdx.x >> 6;
    if (lane == 0) sred[wid] = s;
    __syncthreads();
    if (threadIdx.x == 0) {
        float tot = sred[0] + sred[1] + sred[2] + sred[3];
        atomicAdd(out, tot * OUT_SCALE);
    }
}

// ---------------- fallback (tiny ws): slow but correct ----------------
__global__ void zero_out(float* out) { out[0] = 0.0f; }

__global__ __launch_bounds__(256) void chamfer_direct(
    const float* __restrict__ x, const float* __restrict__ y,
    float* __restrict__ out) {
    const int b   = blockIdx.y;
    const int dir = blockIdx.z;
    const float* A  = (dir == 0) ? x : y;
    const float* Bm = (dir == 0) ? y : x;
    const int i = blockIdx.x * blockDim.x + threadIdx.x;
    const float* abase = A + (size_t)b * 3 * NPTS + i;
    const float ax = abase[0], ay = abase[NPTS], az = abase[2 * NPTS];
    const float* bbase = Bm + (size_t)b * 3 * NPTS;
    float vmin = 3.4e38f;
#pragma unroll 8
    for (int m = 0; m < NPTS; ++m) {
        float dx = ax - bbase[m];
        float dy = ay - bbase[NPTS + m];
        float dz = az - bbase[2 * NPTS + m];
        float t = dx * dx;
        t = fmaf(dy, dy, t);
        t = fmaf(dz, dz, t);
        vmin = fminf(vmin, t);
    }
    float s = vmin;
#pragma unroll
    for (int off = 32; off > 0; off >>= 1) s += __shfl_down(s, off, 64);
    if ((threadIdx.x & 63) == 0) atomicAdd(out, s * OUT_SCALE);
}

extern "C" void kernel_launch(void* const* d_in, const int* in_sizes, int n_in,
                              void* d_out, int out_size, void* d_ws, size_t ws_size,
                              hipStream_t stream) {
    const float* x = (const float*)d_in[0];
    const float* y = (const float*)d_in[1];
    float* out  = (float*)d_out;
    float* pmin = (float*)d_ws;

    const dim3 blk(256);
    const int gx = NPTS / (256 * IPT);                     // 4

    const size_t need32 = 2ull * NB * 32 * NPTS * sizeof(float);   // 8 MiB
    const size_t need8  = 2ull * NB * 8  * NPTS * sizeof(float);   // 2 MiB

    if (ws_size >= need32) {
        chamfer_main<32><<<dim3(gx, NB, 2 * 32), blk, 0, stream>>>(x, y, pmin, out);
        chamfer_reduce<32><<<dim3((2 * NB * NPTS) / 256), blk, 0, stream>>>(pmin, out);
    } else if (ws_size >= need8) {
        chamfer_main<8><<<dim3(gx, NB, 2 * 8), blk, 0, stream>>>(x, y, pmin, out);
        chamfer_reduce<8><<<dim3((2 * NB * NPTS) / 256), blk, 0, stream>>>(pmin, out);
    } else {
        zero_out<<<dim3(1), dim3(1), 0, stream>>>(out);
        chamfer_direct<<<dim3(NPTS / 256, NB, 2), blk, 0, stream>>>(x, y, out);
    }
}

// Round 4
// 83.495 us; speedup vs baseline: 6.3707x; 1.0503x over previous
//
#include <hip/hip_runtime.h>

#define NB 8
#define NPTS 4096
#define IPT 8                       // a-points per thread (4 float2 pairs)
#define NPAIR (IPT / 2)
#define OUT_SCALE (1.0f / (float)(NPTS * NB))

typedef float v2f __attribute__((ext_vector_type(2)));

#if defined(__has_builtin) && __has_builtin(__builtin_elementwise_fma)
#define V2FMA(a, b, c) __builtin_elementwise_fma((a), (b), (c))
#else
static __device__ inline v2f V2FMA(v2f a, v2f b, v2f c) {
    v2f r; r.x = fmaf(a.x, b.x, c.x); r.y = fmaf(a.y, b.y, c.y); return r;
}
#endif
#if defined(__has_builtin) && __has_builtin(__builtin_elementwise_min)
#define V2MIN(a, b) __builtin_elementwise_min((a), (b))
#else
static __device__ inline v2f V2MIN(v2f a, v2f b) {
    v2f r; r.x = fminf(a.x, b.x); r.y = fminf(a.y, b.y); return r;
}
#endif

// ---------------- main: grid (NPTS/(256*IPT), NB, 2*CH), block 256 ----------------
// LDS per m (pre-splatted for packed-f32 operands): {-2bx,-2bx},{-2by,-2by},{-2bz,-2bz},{||b||^2,||b||^2}
// d(a,b) = ||a||^2 + [ ||b||^2 - 2 a.b ]; loop minimizes the bracket, ||a||^2 added in epilogue.
template <int CH_>
__global__ __launch_bounds__(256) void chamfer_main(
    const float* __restrict__ x, const float* __restrict__ y,
    float* __restrict__ pmin, float* __restrict__ out) {
    constexpr int MCHUNK = NPTS / CH_;
    __shared__ v2f qs[MCHUNK * 4];

    const int b   = blockIdx.y;
    const int z   = blockIdx.z;          // 0 .. 2*CH-1
    const int dir = z / CH_;
    const int ch  = z % CH_;
    const int tid = threadIdx.x;

    const float* A = (dir == 0) ? x : y;
    const float* B = (dir == 0) ? y : x;

    // d_out is re-poisoned before every call; zero it (reduce runs strictly after).
    if (blockIdx.x == 0 && b == 0 && z == 0 && tid == 0) out[0] = 0.0f;

    // Stage chunk into LDS, splatted.
    const float* bb = B + (size_t)b * 3 * NPTS + (size_t)ch * MCHUNK;
    for (int t = tid; t < MCHUNK; t += 256) {
        float bxv = bb[t];
        float byv = bb[NPTS + t];
        float bzv = bb[2 * NPTS + t];
        float w = bxv * bxv + byv * byv + bzv * bzv;
        qs[4 * t + 0] = v2f{-2.0f * bxv, -2.0f * bxv};
        qs[4 * t + 1] = v2f{-2.0f * byv, -2.0f * byv};
        qs[4 * t + 2] = v2f{-2.0f * bzv, -2.0f * bzv};
        qs[4 * t + 3] = v2f{w, w};
    }

    // Load IPT a-points as NPAIR float2 pairs (coalesced: element e of pair p is point i0+(2p+e)*256).
    const int i0 = blockIdx.x * (256 * IPT) + tid;
    const float* ab = A + (size_t)b * 3 * NPTS;
    v2f ax2[NPAIR], ay2[NPAIR], az2[NPAIR], xx2[NPAIR], vmin2[NPAIR];
#pragma unroll
    for (int p = 0; p < NPAIR; ++p) {
        int ia = i0 + (2 * p) * 256;
        int ib = i0 + (2 * p + 1) * 256;
        ax2[p] = v2f{ab[ia],            ab[ib]};
        ay2[p] = v2f{ab[NPTS + ia],     ab[NPTS + ib]};
        az2[p] = v2f{ab[2 * NPTS + ia], ab[2 * NPTS + ib]};
        xx2[p] = V2FMA(ax2[p], ax2[p], V2FMA(ay2[p], ay2[p], az2[p] * az2[p]));
        vmin2[p] = v2f{3.4e38f, 3.4e38f};
    }
    __syncthreads();

    // Inner scan: 2 m per iteration; per pair: 6 v_pk_fma_f32 + min tree.
    for (int m = 0; m < MCHUNK; m += 2) {
        v2f cx0 = qs[4 * m + 0], cy0 = qs[4 * m + 1], cz0 = qs[4 * m + 2], cw0 = qs[4 * m + 3];
        v2f cx1 = qs[4 * m + 4], cy1 = qs[4 * m + 5], cz1 = qs[4 * m + 6], cw1 = qs[4 * m + 7];
#pragma unroll
        for (int p = 0; p < NPAIR; ++p) {
            v2f t0 = V2FMA(ax2[p], cx0, cw0);
            t0 = V2FMA(ay2[p], cy0, t0);
            t0 = V2FMA(az2[p], cz0, t0);
            v2f t1 = V2FMA(ax2[p], cx1, cw1);
            t1 = V2FMA(ay2[p], cy1, t1);
            t1 = V2FMA(az2[p], cz1, t1);
            vmin2[p] = V2MIN(vmin2[p], V2MIN(t0, t1));   // scalar lowering -> v_min3 expected
        }
    }

    // Epilogue: add ||a||^2, write partial mins (coalesced in i).
    float* pout = pmin + ((size_t)(dir * NB + b) * CH_ + ch) * NPTS;
#pragma unroll
    for (int p = 0; p < NPAIR; ++p) {
        v2f r = vmin2[p] + xx2[p];
        pout[i0 + (2 * p) * 256]     = r.x;
        pout[i0 + (2 * p + 1) * 256] = r.y;
    }
}

// ---------------- reduce: min over CH chunks, sum all, one atomic/block ----------------
template <int CH_>
__global__ __launch_bounds__(256) void chamfer_reduce(
    const float* __restrict__ pmin, float* __restrict__ out) {
    __shared__ float sred[4];
    const int u  = blockIdx.x * 256 + threadIdx.x;     // 0 .. 2*NB*NPTS-1
    const int i  = u & (NPTS - 1);
    const int db = u >> 12;                            // dir*NB+b
    const float* base = pmin + (size_t)db * CH_ * NPTS + i;
    float vm = base[0];
#pragma unroll
    for (int c = 1; c < CH_; ++c) vm = fminf(vm, base[(size_t)c * NPTS]);

    float s = vm;
#pragma unroll
    for (int off = 32; off > 0; off >>= 1) s += __shfl_down(s, off, 64);
    const int lane = threadIdx.x & 63;
    const int wid  = threadIdx.x >> 6;
    if (lane == 0) sred[wid] = s;
    __syncthreads();
    if (threadIdx.x == 0) {
        float tot = sred[0] + sred[1] + sred[2] + sred[3];
        atomicAdd(out, tot * OUT_SCALE);
    }
}

// ---------------- fallback (tiny ws): slow but correct ----------------
__global__ void zero_out(float* out) { out[0] = 0.0f; }

__global__ __launch_bounds__(256) void chamfer_direct(
    const float* __restrict__ x, const float* __restrict__ y,
    float* __restrict__ out) {
    const int b   = blockIdx.y;
    const int dir = blockIdx.z;
    const float* A  = (dir == 0) ? x : y;
    const float* Bm = (dir == 0) ? y : x;
    const int i = blockIdx.x * blockDim.x + threadIdx.x;
    const float* abase = A + (size_t)b * 3 * NPTS + i;
    const float ax = abase[0], ay = abase[NPTS], az = abase[2 * NPTS];
    const float* bbase = Bm + (size_t)b * 3 * NPTS;
    float vmin = 3.4e38f;
#pragma unroll 8
    for (int m = 0; m < NPTS; ++m) {
        float dx = ax - bbase[m];
        float dy = ay - bbase[NPTS + m];
        float dz = az - bbase[2 * NPTS + m];
        float t = dx * dx;
        t = fmaf(dy, dy, t);
        t = fmaf(dz, dz, t);
        vmin = fminf(vmin, t);
    }
    float s = vmin;
#pragma unroll
    for (int off = 32; off > 0; off >>= 1) s += __shfl_down(s, off, 64);
    if ((threadIdx.x & 63) == 0) atomicAdd(out, s * OUT_SCALE);
}

extern "C" void kernel_launch(void* const* d_in, const int* in_sizes, int n_in,
                              void* d_out, int out_size, void* d_ws, size_t ws_size,
                              hipStream_t stream) {
    const float* x = (const float*)d_in[0];
    const float* y = (const float*)d_in[1];
    float* out  = (float*)d_out;
    float* pmin = (float*)d_ws;

    const dim3 blk(256);
    const int gx = NPTS / (256 * IPT);                     // 2

    const size_t need32 = 2ull * NB * 32 * NPTS * sizeof(float);   // 8 MiB
    const size_t need8  = 2ull * NB * 8  * NPTS * sizeof(float);   // 2 MiB

    if (ws_size >= need32) {
        chamfer_main<32><<<dim3(gx, NB, 2 * 32), blk, 0, stream>>>(x, y, pmin, out);
        chamfer_reduce<32><<<dim3((2 * NB * NPTS) / 256), blk, 0, stream>>>(pmin, out);
    } else if (ws_size >= need8) {
        chamfer_main<8><<<dim3(gx, NB, 2 * 8), blk, 0, stream>>>(x, y, pmin, out);
        chamfer_reduce<8><<<dim3((2 * NB * NPTS) / 256), blk, 0, stream>>>(pmin, out);
    } else {
        zero_out<<<dim3(1), dim3(1), 0, stream>>>(out);
        chamfer_direct<<<dim3(NPTS / 256, NB, 2), blk, 0, stream>>>(x, y, out);
    }
}